// Round 20
// baseline (43.855 us; speedup 1.0000x reference)
//
#include <hip/hip_runtime.h>
#include <hip/hip_bf16.h>

#define NNODES 50000
#define NEDGES 200000
#define WCT_ROWB 1088                    // dense f16 row bytes (544 * 2)
#define WCT_BYTES (32 * WCT_ROWB)        // 34816
#define HROW 40                          // h row stride in f16 units (80B)
#define MTILE 128                        // edges per macro-tile (4 waves x 32)
#define GEMM_BLOCKS ((NEDGES + 2*MTILE - 1) / (2*MTILE))  // 782

// workspace layout (bytes, 16B-aligned)
#define MSG_OFF   0                      // f32[200000*32] natural layout msg[e][32]
#define HEAD_OFF  25600000               // u32[50000]
#define NEXT_OFF  25800000               // u32[200000]
#define WCT_OFF   26600000               // f16[32*544], rows swizzled in [0,1024) only

using f32x16 = __attribute__((ext_vector_type(16))) float;
using f16x2  = __attribute__((ext_vector_type(2))) _Float16;
using f16x4  = __attribute__((ext_vector_type(4))) _Float16;
using f16x8  = __attribute__((ext_vector_type(8))) _Float16;

__device__ __forceinline__ f16x2 pkrtz(float a, float b) {
    return __builtin_bit_cast(f16x2, __builtin_amdgcn_cvt_pkrtz(a, b));
}

__device__ __forceinline__ void gload_lds16(const void* g, void* l) {
    __builtin_amdgcn_global_load_lds(
        (const __attribute__((address_space(1))) unsigned int*)g,
        (__attribute__((address_space(3))) unsigned int*)l, 16, 0, 0);
}

// ---- D1: swizzled wct build (blocks 0..67) + head init (blocks 68..) ----
#define WCT_BLKS 68
__global__ void init_kernel(const float* __restrict__ W_edge,
                            const float* __restrict__ b_edge,
                            unsigned short* __restrict__ wct,
                            unsigned* __restrict__ head) {
    int b = blockIdx.x;
    if (b < WCT_BLKS) {
        int gid = b * 256 + threadIdx.x;       // 0 .. 17407 (= 32*544 exactly)
        int n = gid / 544;
        int c = gid - n * 544;
        float v;
        if (c < 512) v = W_edge[(c & 15) * 1024 + (c >> 4) * 32 + n];
        else         v = b_edge[(c - 512) * 32 + n];
        // swizzle ONLY the 1024B main region (a multiple of 128B); the 64B
        // bias region [1024,1088) cannot absorb a bit-6 XOR (row overflow bug).
        unsigned byte_off = (unsigned)(c * 2);
        if (c < 512) byte_off ^= ((((unsigned)n >> 1) & 7u) << 4);
        f16x2 pv = pkrtz(v, v);
        wct[((unsigned)n * WCT_ROWB + byte_off) >> 1] =
            (unsigned short)(__builtin_bit_cast(unsigned, pv) & 0xffffu);
    } else {
        int gid = (b - WCT_BLKS) * 256 + threadIdx.x;
        if (gid < NNODES) head[gid] = 0xFFFFFFFFu;
    }
}

// ---- D2: 32x32x16 MFMA, 2 pipelined 128-edge macro-tiles, fused scatter ----
__global__ __launch_bounds__(256, 3) void work_kernel(
    const float* __restrict__ feat, const float* __restrict__ efeat,
    const int* __restrict__ src, const int* __restrict__ dst,
    const unsigned short* __restrict__ wct_g,
    float* __restrict__ msg, unsigned* __restrict__ head,
    unsigned* __restrict__ next) {

    __shared__ __align__(16) unsigned short wct_lds[32 * 544];   // 34816 B
    __shared__ __align__(16) unsigned short h_lds[MTILE * HROW]; // 10240 B
    // total 45056 B -> 3 blocks/CU

    const int t = threadIdx.x;
    const int lane = t & 63;
    const int wave = t >> 6;
    const int r32 = lane & 31;           // A row (edge), B/D col (out chan)
    const int kg  = lane >> 5;           // k-group 0/1
    const int wbase = wave * 32;         // wave's 32-edge base in macro-tile
    const int et = t >> 1, p = t & 1;    // h-staging role: edge et, half p

    const int ebase0 = blockIdx.x * (2 * MTILE);
    const int ebase1 = ebase0 + MTILE;
    const bool has1 = (ebase1 < NEDGES);

    // Stage swizzled WcT global->LDS async (linear dest; 34 x 1KB chunks)
    {
        const char* gsrc = (const char*)wct_g;
        char* lbase = (char*)wct_lds;
        #pragma unroll
        for (int c = 0; c < 9; ++c) {
            int chunk = wave + c * 4;
            if (chunk < 34) {
                int boff = (chunk << 10) + lane * 16;
                gload_lds16(gsrc + boff, lbase + boff);
            }
        }
    }

    // Fused chain-scatter for this block's 256 edges (overlaps wct staging)
    {
        int e = ebase0 + t;
        if (e < NEDGES)
            next[e] = atomicExch(&head[dst[e]], (unsigned)e);
    }

    // ---- issue-early loads ----
    const int eg0 = ebase0 + wbase + r32;
    const int eg0c = eg0 < NEDGES ? eg0 : NEDGES - 1;
    const int eg1 = ebase1 + wbase + r32;
    const int eg1c = eg1 < NEDGES ? eg1 : NEDGES - 1;
    const int eh0 = ebase0 + et;  const int eh0c = eh0 < NEDGES ? eh0 : NEDGES - 1;
    const int eh1 = ebase1 + et;  const int eh1c = eh1 < NEDGES ? eh1 : NEDGES - 1;

    const int se0 = src[eh0c];
    const int se1 = src[eh1c];           // T1 src prefetch

    float4 ea0, eb0, ea1, eb1;
    {
        const float* efp = efeat + (size_t)eg0c * 16 + kg * 8;
        ea0 = *(const float4*)efp; eb0 = *(const float4*)(efp + 4);
    }
    {
        const float* efp = efeat + (size_t)eg1c * 16 + kg * 8;
        ea1 = *(const float4*)efp; eb1 = *(const float4*)(efp + 4);
    }

    // T0 h stage (f32 -> f16): thread covers edge et, 16 floats of half p
    {
        const float* fp = feat + (size_t)se0 * 32 + p * 16;
        float4 a = *(const float4*)fp;
        float4 b = *(const float4*)(fp + 4);
        float4 c = *(const float4*)(fp + 8);
        float4 d = *(const float4*)(fp + 12);
        uint4 h0, h1;
        h0.x = __builtin_bit_cast(unsigned, pkrtz(a.x, a.y));
        h0.y = __builtin_bit_cast(unsigned, pkrtz(a.z, a.w));
        h0.z = __builtin_bit_cast(unsigned, pkrtz(b.x, b.y));
        h0.w = __builtin_bit_cast(unsigned, pkrtz(b.z, b.w));
        h1.x = __builtin_bit_cast(unsigned, pkrtz(c.x, c.y));
        h1.y = __builtin_bit_cast(unsigned, pkrtz(c.z, c.w));
        h1.z = __builtin_bit_cast(unsigned, pkrtz(d.x, d.y));
        h1.w = __builtin_bit_cast(unsigned, pkrtz(d.z, d.w));
        char* hb = (char*)h_lds + et * 80 + p * 32;
        *(uint4*)(void*)hb = h0;
        *(uint4*)(void*)(hb + 16) = h1;
    }

    f16x2 ef2[4] = { pkrtz(ea0.x, ea0.y), pkrtz(ea0.z, ea0.w),
                     pkrtz(eb0.x, eb0.y), pkrtz(eb0.z, eb0.w) };

    __syncthreads();   // drains wct global_load_lds (cross-wave) + h0 ds_writes

    const char* browb = (const char*)wct_lds + r32 * WCT_ROWB;
    const unsigned swz = (((unsigned)r32 >> 1) & 7u) << 4;

    // ---- T0: h row -> regs ----
    unsigned hw[16];
    {
        const char* hrb = (const char*)h_lds + (wbase + r32) * 80;
        #pragma unroll
        for (int q = 0; q < 4; ++q) {
            uint4 v = *(const uint4*)(void*)(hrb + q * 16);
            hw[q*4+0] = v.x; hw[q*4+1] = v.y; hw[q*4+2] = v.z; hw[q*4+3] = v.w;
        }
    }

    // ---- issue T1 feat gather NOW (hides under T0 compute) ----
    float4 f1a, f1b, f1c, f1d;
    {
        const float* fp = feat + (size_t)se1 * 32 + p * 16;
        f1a = *(const float4*)fp;
        f1b = *(const float4*)(fp + 4);
        f1c = *(const float4*)(fp + 8);
        f1d = *(const float4*)(fp + 12);
    }

    f32x16 acc = {};

    // X[e, c] = h[i]*ef[kk], c = s*16 + kg*8 + j  =>  i = s, kk = kg*8+j
    #pragma unroll
    for (int s = 0; s < 32; ++s) {
        f16x8 b = *(const f16x8*)(void*)(browb + (((unsigned)(s * 32 + kg * 16)) ^ swz));
        unsigned w = hw[s >> 1];
        unsigned x = (s & 1) ? (w >> 16) : (w & 0xffffu);
        f16x2 hb = __builtin_bit_cast(f16x2, x | (x << 16));
        f16x2 p0 = hb * ef2[0], p1 = hb * ef2[1], p2 = hb * ef2[2], p3 = hb * ef2[3];
        f16x4 lo  = __builtin_shufflevector(p0, p1, 0, 1, 2, 3);
        f16x4 hi4 = __builtin_shufflevector(p2, p3, 0, 1, 2, 3);
        f16x8 af  = __builtin_shufflevector(lo, hi4, 0, 1, 2, 3, 4, 5, 6, 7);
        acc = __builtin_amdgcn_mfma_f32_32x32x16_f16(af, b, acc, 0, 0, 0);
    }
    #pragma unroll
    for (int s = 0; s < 2; ++s) {   // bias extension: X[e, 512+i] = h[i]; UNswizzled
        uint4 av;
        av.x = kg ? hw[s*8+4] : hw[s*8+0];
        av.y = kg ? hw[s*8+5] : hw[s*8+1];
        av.z = kg ? hw[s*8+6] : hw[s*8+2];
        av.w = kg ? hw[s*8+7] : hw[s*8+3];
        f16x8 af = __builtin_bit_cast(f16x8, av);
        f16x8 b = *(const f16x8*)(void*)(browb + 1024 + s * 32 + kg * 16);
        acc = __builtin_amdgcn_mfma_f32_32x32x16_f16(af, b, acc, 0, 0, 0);
    }

    // D (m74/m101): col = lane&31, row = (r&3) + 8*(r>>2) + 4*kg
    #pragma unroll
    for (int r = 0; r < 16; ++r) {
        int drow = (r & 3) + 8 * (r >> 2) + 4 * kg;
        int edge = ebase0 + wbase + drow;
        if (edge < NEDGES) msg[(size_t)edge * 32 + r32] = acc[r];
    }

    if (!has1) return;

    // ---- T1: stage h from regs (wave-private rows; same-wave fence only) ----
    {
        uint4 h0, h1;
        h0.x = __builtin_bit_cast(unsigned, pkrtz(f1a.x, f1a.y));
        h0.y = __builtin_bit_cast(unsigned, pkrtz(f1a.z, f1a.w));
        h0.z = __builtin_bit_cast(unsigned, pkrtz(f1b.x, f1b.y));
        h0.w = __builtin_bit_cast(unsigned, pkrtz(f1b.z, f1b.w));
        h1.x = __builtin_bit_cast(unsigned, pkrtz(f1c.x, f1c.y));
        h1.y = __builtin_bit_cast(unsigned, pkrtz(f1c.z, f1c.w));
        h1.z = __builtin_bit_cast(unsigned, pkrtz(f1d.x, f1d.y));
        h1.w = __builtin_bit_cast(unsigned, pkrtz(f1d.z, f1d.w));
        char* hb = (char*)h_lds + et * 80 + p * 32;
        *(uint4*)(void*)hb = h0;
        *(uint4*)(void*)(hb + 16) = h1;
    }
    asm volatile("s_waitcnt lgkmcnt(0)" ::: "memory");   // rule #18
    __builtin_amdgcn_sched_barrier(0);

    ef2[0] = pkrtz(ea1.x, ea1.y); ef2[1] = pkrtz(ea1.z, ea1.w);
    ef2[2] = pkrtz(eb1.x, eb1.y); ef2[3] = pkrtz(eb1.z, eb1.w);

    {
        const char* hrb = (const char*)h_lds + (wbase + r32) * 80;
        #pragma unroll
        for (int q = 0; q < 4; ++q) {
            uint4 v = *(const uint4*)(void*)(hrb + q * 16);
            hw[q*4+0] = v.x; hw[q*4+1] = v.y; hw[q*4+2] = v.z; hw[q*4+3] = v.w;
        }
    }

    acc = (f32x16){};

    #pragma unroll
    for (int s = 0; s < 32; ++s) {
        f16x8 b = *(const f16x8*)(void*)(browb + (((unsigned)(s * 32 + kg * 16)) ^ swz));
        unsigned w = hw[s >> 1];
        unsigned x = (s & 1) ? (w >> 16) : (w & 0xffffu);
        f16x2 hb = __builtin_bit_cast(f16x2, x | (x << 16));
        f16x2 p0 = hb * ef2[0], p1 = hb * ef2[1], p2 = hb * ef2[2], p3 = hb * ef2[3];
        f16x4 lo  = __builtin_shufflevector(p0, p1, 0, 1, 2, 3);
        f16x4 hi4 = __builtin_shufflevector(p2, p3, 0, 1, 2, 3);
        f16x8 af  = __builtin_shufflevector(lo, hi4, 0, 1, 2, 3, 4, 5, 6, 7);
        acc = __builtin_amdgcn_mfma_f32_32x32x16_f16(af, b, acc, 0, 0, 0);
    }
    #pragma unroll
    for (int s = 0; s < 2; ++s) {   // bias extension, UNswizzled region
        uint4 av;
        av.x = kg ? hw[s*8+4] : hw[s*8+0];
        av.y = kg ? hw[s*8+5] : hw[s*8+1];
        av.z = kg ? hw[s*8+6] : hw[s*8+2];
        av.w = kg ? hw[s*8+7] : hw[s*8+3];
        f16x8 af = __builtin_bit_cast(f16x8, av);
        f16x8 b = *(const f16x8*)(void*)(browb + 1024 + s * 32 + kg * 16);
        acc = __builtin_amdgcn_mfma_f32_32x32x16_f16(af, b, acc, 0, 0, 0);
    }

    #pragma unroll
    for (int r = 0; r < 16; ++r) {
        int drow = (r & 3) + 8 * (r >> 2) + 4 * kg;
        int edge = ebase1 + wbase + drow;
        if (edge < NEDGES) msg[(size_t)edge * 32 + r32] = acc[r];
    }
}

// ---- D3: pull — 8 lanes per node walk the chain; coalesced 128B/edge reads ----
__global__ __launch_bounds__(256) void pull_kernel(
    const float4* __restrict__ msg4, const unsigned* __restrict__ head,
    const unsigned* __restrict__ next, const float* __restrict__ bias,
    float* __restrict__ out) {

    int gid = blockIdx.x * 256 + threadIdx.x;
    if (gid >= NNODES * 8) return;
    int n = gid >> 3, Q = gid & 7;

    float4 s = {0.f, 0.f, 0.f, 0.f};
    float degf = 0.0f;

    unsigned e = head[n];
    while (e != 0xFFFFFFFFu) {
        float4 m = msg4[(size_t)e * 8 + Q];
        s.x += m.x; s.y += m.y; s.z += m.z; s.w += m.w;
        degf += 1.0f;
        e = next[e];
    }

    float inv = 1.0f / fmaxf(degf, 1.0f);
    float4 b = ((const float4*)bias)[Q];
    float4 o = { s.x * inv + b.x, s.y * inv + b.y, s.z * inv + b.z, s.w * inv + b.w };
    *(float4*)(out + n * 32 + Q * 4) = o;
}

extern "C" void kernel_launch(void* const* d_in, const int* in_sizes, int n_in,
                              void* d_out, int out_size, void* d_ws, size_t ws_size,
                              hipStream_t stream) {
    const float* feat   = (const float*)d_in[0];
    const float* efeat  = (const float*)d_in[1];
    const int*   src    = (const int*)d_in[2];
    const int*   dst    = (const int*)d_in[3];
    const float* W_edge = (const float*)d_in[4];
    const float* b_edge = (const float*)d_in[5];
    const float* bias   = (const float*)d_in[6];

    char* ws = (char*)d_ws;
    float*          msg  = (float*)(ws + MSG_OFF);
    unsigned*       head = (unsigned*)(ws + HEAD_OFF);
    unsigned*       next = (unsigned*)(ws + NEXT_OFF);
    unsigned short* wct  = (unsigned short*)(ws + WCT_OFF);
    float*          out  = (float*)d_out;

    init_kernel<<<WCT_BLKS + (NNODES + 255) / 256, 256, 0, stream>>>(
        W_edge, b_edge, wct, head);
    work_kernel<<<GEMM_BLOCKS, 256, 0, stream>>>(
        feat, efeat, src, dst, wct, msg, head, next);
    pull_kernel<<<(NNODES * 8 + 255) / 256, 256, 0, stream>>>(
        (const float4*)msg, head, next, bias, out);
}